// Round 1
// baseline (322.171 us; speedup 1.0000x reference)
//
#include <hip/hip_runtime.h>
#include <math.h>

#define NN 48
#define CC 512
#define KK 64
#define PP 1600
#define EPSF 1e-12f

typedef short short8 __attribute__((ext_vector_type(8)));
typedef float f32x4 __attribute__((ext_vector_type(4)));

static __device__ __forceinline__ unsigned short f2bf(float f) {
    unsigned u = __float_as_uint(f);
    u += 0x7fffu + ((u >> 16) & 1u);   // round-to-nearest-even
    return (unsigned short)(u >> 16);
}
static __device__ __forceinline__ unsigned pack2(float a, float b) {
    return (unsigned)f2bf(a) | ((unsigned)f2bf(b) << 16);
}

// ---------------------------------------------------------------------------
// Kernel 1: fused norm + attn + logits MFMA-GEMM + softmax.
// grid (25, N), block 256 (4 waves). Per block: 64 p (exact: 25*64 = 1600),
// all 512 c. Cross-chunk register prefetch: chunk cs+1's global loads issue
// at the top of iteration cs and are consumed one full iteration later, so
// HBM latency hides under process+MFMA+barriers of the current chunk.
// Emits w'[n,k,p] bf16 (= softmax*hmp*invnorm), wsum[n,k] (LDS-staged then
// one global atomic per k), and optionally xbf = bf16(x) for kn_term1.
// ---------------------------------------------------------------------------
__global__ __launch_bounds__(256, 4) void kn_logits(
    const float* __restrict__ x, const float* __restrict__ conv_w,
    const float* __restrict__ attn_w, const float* __restrict__ attn_b,
    unsigned short* __restrict__ wg, float* __restrict__ wsum,
    unsigned short* __restrict__ xbf)
{
    __shared__ unsigned short xt[64][76];   // [c_local][p] bf16, 152B rows (8B-aligned, 2-way max)
    __shared__ unsigned short cwb[64][72];  // [k][c_local] bf16, 144B rows
    __shared__ float attn_l[CC];
    __shared__ float red[16][64];
    __shared__ float invn_l[64];
    __shared__ float hmp_l[64];
    __shared__ float wsum_l[KK];

    const int n = blockIdx.y, p0 = blockIdx.x * 64, tid = threadIdx.x;
    const int q = tid & 15, cg = tid >> 4;        // x staging: p-quad, c-row-group
    const int wave = tid >> 6, lane = tid & 63;
    const int lq = lane >> 4, lm = lane & 15;     // MFMA lane decomposition
    const int kr = tid >> 2, cq = tid & 3;        // conv_w staging map

    for (int i = tid; i < CC; i += 256) attn_l[i] = attn_w[i];
    if (tid < KK) wsum_l[tid] = 0.f;

    f32x4 acc[4];
#pragma unroll
    for (int mt = 0; mt < 4; ++mt) acc[mt] = (f32x4){0.f, 0.f, 0.f, 0.f};
    float ss[4] = {0.f, 0.f, 0.f, 0.f};
    float ad[4] = {0.f, 0.f, 0.f, 0.f};

    const float* xb = x + (size_t)n * CC * PP;
    const float* wp0 = conv_w + (size_t)kr * CC + cq * 16;
    const float* xp0 = xb + (size_t)(cg * 4) * PP + p0 + 4 * q;

    // prologue: issue chunk-0 loads (in flight across the attn_l barrier)
    float4 wv[4], xv[4];
#pragma unroll
    for (int j = 0; j < 4; ++j) wv[j] = *(const float4*)(wp0 + 4 * j);
#pragma unroll
    for (int j = 0; j < 4; ++j) xv[j] = *(const float4*)(xp0 + (size_t)j * PP);

    __syncthreads();   // attn_l / wsum_l ready

#pragma unroll 1
    for (int cs = 0; cs < 8; ++cs) {
        // issue chunk cs+1 loads FIRST (before any store -> counted vmcnt
        // lets the compiler wait on loads without draining stores)
        float4 wn[4], xn_[4];
        if (cs < 7) {
            const float* wp = wp0 + (cs + 1) * 64;
            const float* xp = xp0 + (size_t)(cs + 1) * 64 * PP;
#pragma unroll
            for (int j = 0; j < 4; ++j) wn[j] = *(const float4*)(wp + 4 * j);
#pragma unroll
            for (int j = 0; j < 4; ++j) xn_[j] = *(const float4*)(xp + (size_t)j * PP);
        }
        // process conv_w tile (loaded last iteration) -> bf16 LDS
#pragma unroll
        for (int j = 0; j < 4; ++j) {
            uint2 u = {pack2(wv[j].x, wv[j].y), pack2(wv[j].z, wv[j].w)};
            *(uint2*)&cwb[kr][cq * 16 + 4 * j] = u;
        }
        // process x tile: stats + bf16 LDS + bf16 global writeback
        const int cbase = cs * 64 + cg * 4;
#pragma unroll
        for (int j = 0; j < 4; ++j) {
            float4 v = xv[j];
            const float aw = attn_l[cbase + j];
            ss[0] += v.x * v.x; ss[1] += v.y * v.y;
            ss[2] += v.z * v.z; ss[3] += v.w * v.w;
            ad[0] += fmaxf(v.x, 0.f) * aw; ad[1] += fmaxf(v.y, 0.f) * aw;
            ad[2] += fmaxf(v.z, 0.f) * aw; ad[3] += fmaxf(v.w, 0.f) * aw;
            uint2 u = {pack2(v.x, v.y), pack2(v.z, v.w)};
            *(uint2*)&xt[cg * 4 + j][4 * q] = u;
            if (xbf)
                *(uint2*)(xbf + ((size_t)n * CC + cbase + j) * PP + p0 + 4 * q) = u;
        }
        __syncthreads();
#pragma unroll
        for (int ks = 0; ks < 2; ++ks) {
            short8 af[4];
#pragma unroll
            for (int mt = 0; mt < 4; ++mt)
                af[mt] = *(const short8*)&cwb[mt * 16 + lm][ks * 32 + lq * 8];
            const int pl = wave * 16 + lm;
            const int cb = ks * 32 + lq * 8;
            short8 bv;
#pragma unroll
            for (int j = 0; j < 8; ++j) bv[j] = (short)xt[cb + j][pl];
#pragma unroll
            for (int mt = 0; mt < 4; ++mt)
                acc[mt] = __builtin_amdgcn_mfma_f32_16x16x32_bf16(
                    af[mt], bv, acc[mt], 0, 0, 0);
        }
        __syncthreads();
        if (cs < 7) {
#pragma unroll
            for (int j = 0; j < 4; ++j) { wv[j] = wn[j]; xv[j] = xn_[j]; }
        }
    }

    // block reductions: invnorm and hmp per p (fp32)
#pragma unroll
    for (int j = 0; j < 4; ++j) red[cg][4 * q + j] = ss[j];
    __syncthreads();
    if (tid < 64) {
        float S = 0.f;
#pragma unroll
        for (int l = 0; l < 16; ++l) S += red[l][tid];
        invn_l[tid] = 1.f / fmaxf(sqrtf(S), EPSF);
    }
    __syncthreads();
#pragma unroll
    for (int j = 0; j < 4; ++j) red[cg][4 * q + j] = ad[j];
    __syncthreads();
    if (tid < 64) {
        float A = 0.f;
#pragma unroll
        for (int l = 0; l < 16; ++l) A += red[l][tid];
        hmp_l[tid] = fmaxf(A + attn_b[0], 0.f);
    }
    __syncthreads();

    // softmax over k=64 per p, entirely in registers (C-layout + shfl_xor)
    const int pl = wave * 16 + lm;
    const float inv = invn_l[pl];
    const float hp = hmp_l[pl];
    float mx = -1e30f;
#pragma unroll
    for (int mt = 0; mt < 4; ++mt)
#pragma unroll
        for (int r = 0; r < 4; ++r) {
            const float l = acc[mt][r] * inv;
            acc[mt][r] = l;
            mx = fmaxf(mx, l);
        }
    mx = fmaxf(mx, __shfl_xor(mx, 16));
    mx = fmaxf(mx, __shfl_xor(mx, 32));
    float s = 0.f;
#pragma unroll
    for (int mt = 0; mt < 4; ++mt)
#pragma unroll
        for (int r = 0; r < 4; ++r) {
            const float e = __expf(acc[mt][r] - mx);
            acc[mt][r] = e;
            s += e;
        }
    s += __shfl_xor(s, 16);
    s += __shfl_xor(s, 32);
    const float sden = hp / s;

    unsigned short* wrb = wg + (size_t)n * KK * PP + p0;
#pragma unroll
    for (int mt = 0; mt < 4; ++mt)
#pragma unroll
        for (int r = 0; r < 4; ++r) {
            const int k = mt * 16 + lq * 4 + r;
            const float w0 = acc[mt][r] * sden;
            float wk = w0;
#pragma unroll
            for (int o = 1; o < 16; o <<= 1) wk += __shfl_xor(wk, o);
            if (lm == 0) atomicAdd(&wsum_l[k], wk);
            wrb[(size_t)k * PP + pl] = f2bf(w0 * inv);
        }
    __syncthreads();
    if (tid < KK) atomicAdd(&wsum[n * KK + tid], wsum_l[tid]);
}

// ---------------------------------------------------------------------------
// Kernel 2: term1[k,c] = sum_p w'[k,p] * x[c,p] via MFMA (contraction over p;
// both operands p-contiguous -> b128 fragments). grid (8 c-chunks, N, 4 p-
// chunks) = 1536 blocks (6/CU). Software-pipelined staging (1-deep register
// prefetch). XB: x from bf16 sidecar; else convert fp32 x inline.
// ---------------------------------------------------------------------------
template <bool XB>
__global__ __launch_bounds__(256) void kn_term1(
    const float* __restrict__ xf, const unsigned short* __restrict__ xbf,
    const unsigned short* __restrict__ wgq, float* __restrict__ term1p)
{
    __shared__ unsigned short wt[64][40];    // [k][32p] bf16, rows 80B
    __shared__ unsigned short xt2[64][40];   // [c_local][32p] bf16
    const int c0 = blockIdx.x * 64, n = blockIdx.y, ph = blockIdx.z;
    const int tid = threadIdx.x;
    const int wave = tid >> 6, lane = tid & 63, lq = lane >> 4, lm = lane & 15;
    const int koff = (wave >> 1) * 32, coff = (wave & 1) * 32;
    const int s_begin = (50 * ph) >> 2, s_end = (50 * (ph + 1)) >> 2;
    const int rA = tid >> 2, cq = tid & 3;   // staging map (same for A and B)

    f32x4 acc[2][2];
#pragma unroll
    for (int mt = 0; mt < 2; ++mt)
#pragma unroll
        for (int nt = 0; nt < 2; ++nt) acc[mt][nt] = (f32x4){0.f, 0.f, 0.f, 0.f};

    const unsigned short* wb = wgq + (size_t)n * KK * PP + (size_t)rA * PP + cq * 8;
    const unsigned short* xbb = xbf + ((size_t)n * CC + c0 + rA) * PP + cq * 8;
    const float* xfb = xf + ((size_t)n * CC + c0 + rA) * PP + cq * 8;

    auto ldB = [&](int p) -> uint4 {
        if (XB) {
            return *(const uint4*)(xbb + p);
        } else {
            const float* sp = xfb + p;
            float4 a = *(const float4*)sp, b = *(const float4*)(sp + 4);
            return make_uint4(pack2(a.x, a.y), pack2(a.z, a.w),
                              pack2(b.x, b.y), pack2(b.z, b.w));
        }
    };

    uint4 pa = *(const uint4*)(wb + s_begin * 32);
    uint4 pb = ldB(s_begin * 32);

    for (int ps = s_begin; ps < s_end; ++ps) {
        *(uint4*)&wt[rA][cq * 8] = pa;
        *(uint4*)&xt2[rA][cq * 8] = pb;
        __syncthreads();
        if (ps + 1 < s_end) {                 // prefetch next tile (overlaps MFMA)
            pa = *(const uint4*)(wb + (ps + 1) * 32);
            pb = ldB((ps + 1) * 32);
        }
        short8 af[2], bv[2];
#pragma unroll
        for (int mt = 0; mt < 2; ++mt)
            af[mt] = *(const short8*)&wt[koff + mt * 16 + lm][lq * 8];
#pragma unroll
        for (int nt = 0; nt < 2; ++nt)
            bv[nt] = *(const short8*)&xt2[coff + nt * 16 + lm][lq * 8];
#pragma unroll
        for (int mt = 0; mt < 2; ++mt)
#pragma unroll
            for (int nt = 0; nt < 2; ++nt)
                acc[mt][nt] = __builtin_amdgcn_mfma_f32_16x16x32_bf16(
                    af[mt], bv[nt], acc[mt][nt], 0, 0, 0);
        __syncthreads();
    }

    float* ob = term1p + ((size_t)ph * NN + n) * KK * CC + c0 + coff;
#pragma unroll
    for (int mt = 0; mt < 2; ++mt)
#pragma unroll
        for (int r = 0; r < 4; ++r) {
            const int k = koff + mt * 16 + lq * 4 + r;
#pragma unroll
            for (int nt = 0; nt < 2; ++nt)
                ob[(size_t)k * CC + nt * 16 + lm] = acc[mt][nt][r];
        }
}

// ---------------------------------------------------------------------------
// Kernel 3: vlad = sum(term1 partials) - wsum*centroids; intra L2-normalize;
// per-n global sumsq. grid (K, N), block 128.
// ---------------------------------------------------------------------------
__global__ __launch_bounds__(128) void kn_vlad(
    const float* __restrict__ term1p, const float* __restrict__ wsum,
    const float* __restrict__ cent, float* __restrict__ out,
    float* __restrict__ nsum)
{
    const int k = blockIdx.x, n = blockIdx.y, tid = threadIdx.x;
    const size_t base = ((size_t)n * KK + k) * CC;
    const size_t NKC = (size_t)NN * KK * CC;
    const float ws = wsum[n * KK + k];
    const int c = tid * 4;

    float4 ce = *(const float4*)(cent + (size_t)k * CC + c);
    float4 v = {-ws * ce.x, -ws * ce.y, -ws * ce.z, -ws * ce.w};
#pragma unroll
    for (int h = 0; h < 4; ++h) {
        float4 a = *(const float4*)(term1p + h * NKC + base + c);
        v.x += a.x; v.y += a.y; v.z += a.z; v.w += a.w;
    }

    float s = v.x * v.x + v.y * v.y + v.z * v.z + v.w * v.w;
#pragma unroll
    for (int o = 32; o >= 1; o >>= 1) s += __shfl_down(s, o, 64);

    __shared__ float rb[2];
    __shared__ float sinv;
    if ((tid & 63) == 0) rb[tid >> 6] = s;
    __syncthreads();
    if (tid == 0) {
        const float S = rb[0] + rb[1];
        const float inv = 1.f / fmaxf(sqrtf(S), EPSF);
        sinv = inv;
        atomicAdd(&nsum[n], S * inv * inv);
    }
    __syncthreads();
    const float inv = sinv;
    float4 o4 = {v.x * inv, v.y * inv, v.z * inv, v.w * inv};
    *(float4*)(out + base + c) = o4;
}

// ---------------------------------------------------------------------------
// Kernel 4: global L2 normalize per n.
// ---------------------------------------------------------------------------
__global__ __launch_bounds__(256) void kn_scale(
    float* __restrict__ out, const float* __restrict__ nsum)
{
    const int n = blockIdx.y;
    const size_t off = ((size_t)blockIdx.x * 256 + threadIdx.x) * 4;
    const float g = 1.f / fmaxf(sqrtf(nsum[n]), EPSF);
    float4 v = *(float4*)(out + (size_t)n * KK * CC + off);
    v.x *= g; v.y *= g; v.z *= g; v.w *= g;
    *(float4*)(out + (size_t)n * KK * CC + off) = v;
}

extern "C" void kernel_launch(void* const* d_in, const int* in_sizes, int n_in,
                              void* d_out, int out_size, void* d_ws, size_t ws_size,
                              hipStream_t stream)
{
    (void)in_sizes; (void)n_in; (void)out_size;
    const float* x      = (const float*)d_in[0];
    const float* conv_w = (const float*)d_in[1];
    const float* attn_w = (const float*)d_in[2];
    const float* attn_b = (const float*)d_in[3];
    const float* cent   = (const float*)d_in[4];
    float* out = (float*)d_out;

    // ws layout: term1p[4][N][K][C] f32 | wsum f32 | nsum f32(pad) | wg bf16 | xbf bf16
    char* w = (char*)d_ws;
    float* term1p = (float*)w;            w += (size_t)4 * NN * KK * CC * 4;
    float* wsum   = (float*)w;            w += (size_t)NN * KK * 4;
    float* nsum   = (float*)w;            w += 256;
    unsigned short* wg  = (unsigned short*)w; w += (size_t)NN * KK * PP * 2;
    unsigned short* xbf = (unsigned short*)w;
    const size_t need_xb = (size_t)(w - (char*)d_ws) + (size_t)NN * CC * PP * 2;
    const bool xb = ws_size >= need_xb;

    hipMemsetAsync(wsum, 0, NN * KK * sizeof(float), stream);
    hipMemsetAsync(nsum, 0, NN * sizeof(float), stream);

    kn_logits<<<dim3(25, NN), 256, 0, stream>>>(x, conv_w, attn_w, attn_b,
                                                wg, wsum, xb ? xbf : nullptr);
    if (xb)
        kn_term1<true><<<dim3(8, NN, 4), 256, 0, stream>>>(x, xbf, wg, term1p);
    else
        kn_term1<false><<<dim3(8, NN, 4), 256, 0, stream>>>(x, xbf, wg, term1p);
    kn_vlad <<<dim3(KK, NN), 128, 0, stream>>>(term1p, wsum, cent, out, nsum);
    kn_scale<<<dim3(32, NN), 256, 0, stream>>>(out, nsum);
}